// Round 7
// baseline (217.022 us; speedup 1.0000x reference)
//
#include <hip/hip_runtime.h>
#include <cfloat>
#include <math.h>

#define BATCH 8
#define CH 256
#define CI 128
#define NPIX 3136   // 56*56
#define NCHUNK 98   // 3136/32 pixel tiles
#define NBIN 128    // value-space bins
#define CSROWS 130  // NBIN rows + zero row (128) + pad
#define BN_EPS 1e-5f

typedef __attribute__((ext_vector_type(8))) short bf16x8;   // 8 bf16 in 4 VGPRs
typedef __attribute__((ext_vector_type(4))) float f32x4;

__device__ __forceinline__ float bf2f(unsigned short u) {
    union { unsigned int i; float f; } x; x.i = ((unsigned int)u) << 16; return x.f;
}
__device__ __forceinline__ unsigned short f2bf(float f) {
    union { float f; unsigned int i; } x; x.f = f;
    unsigned int u = x.i;
    return (unsigned short)((u + 0x7FFFu + ((u >> 16) & 1u)) >> 16);  // RNE
}
// order-preserving float<->uint encoding for atomicMin/Max
__device__ __forceinline__ unsigned fenc(float f) {
    unsigned i = __float_as_uint(f);
    return (i & 0x80000000u) ? ~i : (i | 0x80000000u);
}
__device__ __forceinline__ float fdec(unsigned k) {
    unsigned i = (k & 0x80000000u) ? (k ^ 0x80000000u) : ~k;
    return __uint_as_float(i);
}

// ---------------------------------------------------------------------------
// K1: block 0: fold wf into theta/phi weights (+biases) + init minmax.
// blocks 1-8:  swizzle g_w^T into bf16 B-fragments  (K=256, N=128)
// blocks 9-16: swizzle wz_w^T into bf16 B-fragments (K=128, N=256)
// blocks 17-32: zero the CSP bin table.
// ---------------------------------------------------------------------------
__global__ __launch_bounds__(256) void k_fold(
    const float* __restrict__ wf_w,
    const float* __restrict__ theta_w, const float* __restrict__ theta_b,
    const float* __restrict__ phi_w,   const float* __restrict__ phi_b,
    const float* __restrict__ g_w,     const float* __restrict__ wz_w,
    float* __restrict__ ta_w, float* __restrict__ pb_w, float* __restrict__ biases,
    unsigned* __restrict__ mmx, float* __restrict__ CSP,
    unsigned short* __restrict__ Bfrag_g, unsigned short* __restrict__ Bfrag_w)
{
    const int bk = blockIdx.x, tid = threadIdx.x;
    if (bk == 0) {
        float ta = 0.f, pb = 0.f;
        for (int c = 0; c < CI; ++c) {
            ta += wf_w[c]      * theta_w[c * CH + tid];
            pb += wf_w[CI + c] * phi_w[c * CH + tid];
        }
        ta_w[tid] = ta;
        pb_w[tid] = pb;
        if (tid < BATCH) {
            mmx[2 * tid]     = 0xFFFFFFFFu;  // min-enc init
            mmx[2 * tid + 1] = 0u;           // max-enc init
        }
        if (tid == 0) {
            float tb = 0.f, pbb = 0.f;
            for (int c = 0; c < CI; ++c) {
                tb  += wf_w[c]      * theta_b[c];
                pbb += wf_w[CI + c] * phi_b[c];
            }
            biases[0] = tb;
            biases[1] = pbb;
        }
    } else if (bk <= 8) {
        const int base_pair = (bk - 1) * 8;
        for (int e = tid; e < 4096; e += 256) {
            int pp = e >> 9, lane = (e >> 3) & 63, j = e & 7;
            int pair = base_pair + pp;
            int ks = pair >> 3, nt = pair & 7;
            int k = ks * 32 + (lane >> 4) * 8 + j;
            int n = nt * 16 + (lane & 15);
            Bfrag_g[(size_t)pair * 512 + lane * 8 + j] = f2bf(g_w[n * CH + k]);
        }
    } else if (bk <= 16) {
        const int base_pair = (bk - 9) * 8;
        for (int e = tid; e < 4096; e += 256) {
            int pp = e >> 9, lane = (e >> 3) & 63, j = e & 7;
            int pair = base_pair + pp;
            int ks = pair >> 4, nt = pair & 15;
            int k = ks * 32 + (lane >> 4) * 8 + j;
            int n = nt * 16 + (lane & 15);
            Bfrag_w[(size_t)pair * 512 + lane * 8 + j] = f2bf(wz_w[n * CI + k]);
        }
    } else {
        const int total = BATCH * CSROWS * CI * 2;       // 266240 floats
        const int per   = total / 16;                    // 16640
        const int off   = (bk - 17) * per;
        for (int i = tid; i < per; i += 256) CSP[off + i] = 0.f;
    }
}

// ---------------------------------------------------------------------------
// K2 (fused conv+gemm): x tile -> LDS fp32 -> {fused a/bsc dots + bf16
// transpose} -> MFMA with g_w B-frags -> gxg in PIXEL order (coalesced).
// Also wave-reduces bsc min/max -> 2 global atomics per block.
// grid (98, B), block 256. gout aliases the dead fp32 tile.
// ---------------------------------------------------------------------------
__global__ __launch_bounds__(256) void k_gemm(
    const float* __restrict__ x,
    const unsigned short* __restrict__ Bfrag_g,
    const float* __restrict__ g_b,
    const float* __restrict__ ta_w, const float* __restrict__ pb_w,
    const float* __restrict__ biases,
    unsigned short* __restrict__ gxg,
    float* __restrict__ a_out, float* __restrict__ bsc_out,
    unsigned* __restrict__ mmx)
{
    __shared__ float xs[CH][36];              // 36.9 KB (float4-aligned rows)
    __shared__ unsigned short xsb[32 * 264];  // 16.5 KB bf16 transposed tile
    __shared__ float ra[8][32], rp[8][32];    // 2 KB
    unsigned short* gout = (unsigned short*)&xs[0][0];  // reuse dead xs

    const int b  = blockIdx.y;
    const int n0 = blockIdx.x * 32;
    const int tid = threadIdx.x;

    for (int t = tid; t < CH * 8; t += 256) {
        int c = t >> 3, n4 = t & 7;
        const float4* src = (const float4*)(x + ((size_t)b * CH + c) * NPIX + n0);
        *((float4*)&xs[c][n4 * 4]) = src[n4];
    }
    __syncthreads();

    const int p = tid & 31;        // pixel
    const int g = tid >> 5;        // channel group of 32

    // fused: a/bsc partial dots + bf16 transpose (each xs value read once)
    {
        const int cbase = g * 32;
        float aa = 0.f, pp = 0.f;
        unsigned int* dst = (unsigned int*)&xsb[p * 264 + cbase];
#pragma unroll
        for (int q = 0; q < 16; ++q) {
            float lo = xs[cbase + 2 * q][p];
            float hi = xs[cbase + 2 * q + 1][p];
            aa += ta_w[cbase + 2 * q] * lo + ta_w[cbase + 2 * q + 1] * hi;
            pp += pb_w[cbase + 2 * q] * lo + pb_w[cbase + 2 * q + 1] * hi;
            dst[q] = (unsigned int)f2bf(lo) | ((unsigned int)f2bf(hi) << 16);
        }
        ra[g][p] = aa; rp[g][p] = pp;
    }
    __syncthreads();

    if (tid < 32) {
        float sa = 0.f, sp = 0.f;
#pragma unroll
        for (int gg = 0; gg < 8; ++gg) { sa += ra[gg][tid]; sp += rp[gg][tid]; }
        float av = sa + biases[0];
        float pv = sp + biases[1];
        a_out[b * NPIX + n0 + tid]   = av;
        bsc_out[b * NPIX + n0 + tid] = pv;
        // wave-reduce min/max over the 32 lanes, one atomic pair per block
        float mn = pv, mx = pv;
#pragma unroll
        for (int off = 16; off > 0; off >>= 1) {
            mn = fminf(mn, __shfl_xor(mn, off, 32));
            mx = fmaxf(mx, __shfl_xor(mx, off, 32));
        }
        if (tid == 0) {
            atomicMin(&mmx[2 * b],     fenc(mn));
            atomicMax(&mmx[2 * b + 1], fenc(mx));
        }
    }

    // MFMA: D[px(32) x o(128)] = xsb(32x256) * g_wT(256x128)
    const int w = tid >> 6, l = tid & 63, lm = l & 15, lq = l >> 4;
    f32x4 acc[2][2];
#pragma unroll
    for (int mi = 0; mi < 2; ++mi)
#pragma unroll
        for (int ni = 0; ni < 2; ++ni) acc[mi][ni] = (f32x4){0.f, 0.f, 0.f, 0.f};

#pragma unroll
    for (int ks = 0; ks < 8; ++ks) {
        bf16x8 a0 = *(const bf16x8*)&xsb[lm * 264 + ks * 32 + lq * 8];
        bf16x8 a1 = *(const bf16x8*)&xsb[(16 + lm) * 264 + ks * 32 + lq * 8];
        bf16x8 b0 = *(const bf16x8*)(Bfrag_g + ((size_t)(ks * 8 + w * 2) * 64 + l) * 8);
        bf16x8 b1 = *(const bf16x8*)(Bfrag_g + ((size_t)(ks * 8 + w * 2 + 1) * 64 + l) * 8);
        acc[0][0] = __builtin_amdgcn_mfma_f32_16x16x32_bf16(a0, b0, acc[0][0], 0, 0, 0);
        acc[0][1] = __builtin_amdgcn_mfma_f32_16x16x32_bf16(a0, b1, acc[0][1], 0, 0, 0);
        acc[1][0] = __builtin_amdgcn_mfma_f32_16x16x32_bf16(a1, b0, acc[1][0], 0, 0, 0);
        acc[1][1] = __builtin_amdgcn_mfma_f32_16x16x32_bf16(a1, b1, acc[1][1], 0, 0, 0);
    }
    __syncthreads();   // xs reads done; gout (aliased) safe to write

#pragma unroll
    for (int mi = 0; mi < 2; ++mi)
#pragma unroll
        for (int ni = 0; ni < 2; ++ni) {
            int o = w * 32 + ni * 16 + lm;
            float gb = g_b[o];
#pragma unroll
            for (int r = 0; r < 4; ++r) {
                int m = mi * 16 + lq * 4 + r;
                gout[m * 136 + o] = f2bf(acc[mi][ni][r] + gb);
            }
        }
    __syncthreads();

    {
        const int n = tid >> 3, ch = tid & 7;
        const uint4* s = (const uint4*)&gout[n * 136 + ch * 16];
        uint4* d = (uint4*)(gxg + ((size_t)(b * NPIX + n0 + n)) * CI + ch * 16);
        d[0] = s[0]; d[1] = s[1];
    }
}

// ---------------------------------------------------------------------------
// K3: bin accumulation — streams gxg in pixel order (coalesced), adds each
// row into its value-bin's CSP row via global atomics (bin uniform across
// the row's 128 lanes -> coalesced, no intra-wave contention).
// grid (98, B), block 256.
// ---------------------------------------------------------------------------
__global__ __launch_bounds__(256) void k_binsum(
    const unsigned short* __restrict__ gxg,
    const float* __restrict__ bsc,
    const unsigned* __restrict__ mmx,
    float* __restrict__ CSP)
{
    __shared__ float sval[32];
    __shared__ int   sq[32];
    const int b = blockIdx.y, c = blockIdx.x, tid = threadIdx.x;

    if (tid < 32) {
        float bmin = fdec(mmx[2 * b]);
        float bmax = fdec(mmx[2 * b + 1]);
        float range = bmax - bmin;
        float scale = (range > 0.f) ? (float)NBIN / range : 0.f;
        float v = bsc[b * NPIX + c * 32 + tid];
        int q = (int)((v - bmin) * scale);
        q = (q < 0) ? 0 : ((q > NBIN - 1) ? NBIN - 1 : q);
        sq[tid] = q; sval[tid] = v;
    }
    __syncthreads();

    const int o = tid & 127, h = tid >> 7;
#pragma unroll 4
    for (int i = 0; i < 16; ++i) {
        int rr = h * 16 + i;
        int r = c * 32 + rr;
        float v = bf2f(gxg[((size_t)(b * NPIX + r)) * CI + o]);
        float* base = CSP + ((size_t)(b * CSROWS + sq[rr]) * CI + o) * 2;
        atomicAdd(base,     v);
        atomicAdd(base + 1, sval[rr] * v);
    }
}

// ---------------------------------------------------------------------------
// K4: in-place suffix scan over the 128 bins (float2 rows = 256 floats).
// Zeroes rows 128/129. grid (B), block 256.
// ---------------------------------------------------------------------------
__global__ __launch_bounds__(256) void k_suffix(float* __restrict__ CSP)
{
    const int b = blockIdx.x, tid = threadIdx.x;
    float acc = 0.f;
#pragma unroll 8
    for (int r = NBIN - 1; r >= 0; --r) {
        size_t idx = ((size_t)(b * CSROWS + r) * CI) * 2 + tid;
        acc += CSP[idx];
        CSP[idx] = acc;
    }
    CSP[((size_t)(b * CSROWS + 128) * CI) * 2 + tid] = 0.f;
    CSP[((size_t)(b * CSROWS + 129) * CI) * 2 + tid] = 0.f;
}

// ---------------------------------------------------------------------------
// K5 (fused): direct bin lookup from (bmin,scale) -> y row via ONE float2
// suffix-row load -> MFMA wz-GEMM -> BN -> residual -> out.
// grid (98, B), block 256.
// ---------------------------------------------------------------------------
__global__ __launch_bounds__(256) void k_final(
    const float* __restrict__ x,
    const float* __restrict__ a_arr, const float* __restrict__ wf_b,
    const float* __restrict__ CSP, const unsigned* __restrict__ mmx,
    const unsigned short* __restrict__ Bfrag_w,
    const float* __restrict__ wz_b,
    const float* __restrict__ bn_g, const float* __restrict__ bn_b,
    const float* __restrict__ bn_m, const float* __restrict__ bn_v,
    float* __restrict__ out)
{
    __shared__ unsigned short ys[32 * 136];  // bf16 y tile, pad 136
    __shared__ float Df[32 * 260];           // fp32 D tile, pad 260
    __shared__ int   rs[32];
    __shared__ float ts[32];

    const int b = blockIdx.y;
    const int n0 = blockIdx.x * 32;
    const int tid = threadIdx.x;

    if (tid < 32) {
        float t = a_arr[b * NPIX + n0 + tid] + wf_b[0];
        float bmin = fdec(mmx[2 * b]);
        float bmax = fdec(mmx[2 * b + 1]);
        float range = bmax - bmin;
        float scale = (range > 0.f) ? (float)NBIN / range : 0.f;
        float fq = (-t - bmin) * scale;
        int q = (int)(fq + 0.5f);            // nearest bin edge
        q = (q < 0) ? 0 : ((q > NBIN) ? NBIN : q);  // row NBIN == zero row
        rs[tid] = q;
        ts[tid] = t;
    }
    __syncthreads();

    const int o = tid & 127;
    const int h = tid >> 7;
    const float invN = 1.0f / (float)NPIX;
    const float2* CSP2 = (const float2*)CSP;

#pragma unroll 4
    for (int i = 0; i < 16; ++i) {
        int n = h * 16 + i;
        float2 s = CSP2[(size_t)(b * CSROWS + rs[n]) * CI + o];
        ys[n * 136 + o] = f2bf((ts[n] * s.x + s.y) * invN);
    }
    __syncthreads();

    // MFMA: D[px(32) x cc(256)] = ys(32x128) * wz_wT(128x256)
    const int w = tid >> 6, l = tid & 63, lm = l & 15, lq = l >> 4;
    f32x4 acc[2][4];
#pragma unroll
    for (int mi = 0; mi < 2; ++mi)
#pragma unroll
        for (int ni = 0; ni < 4; ++ni) acc[mi][ni] = (f32x4){0.f, 0.f, 0.f, 0.f};

#pragma unroll
    for (int ks = 0; ks < 4; ++ks) {
        bf16x8 a0 = *(const bf16x8*)&ys[lm * 136 + ks * 32 + lq * 8];
        bf16x8 a1 = *(const bf16x8*)&ys[(16 + lm) * 136 + ks * 32 + lq * 8];
#pragma unroll
        for (int ni = 0; ni < 4; ++ni) {
            bf16x8 bb = *(const bf16x8*)(Bfrag_w + ((size_t)(ks * 16 + w * 4 + ni) * 64 + l) * 8);
            acc[0][ni] = __builtin_amdgcn_mfma_f32_16x16x32_bf16(a0, bb, acc[0][ni], 0, 0, 0);
            acc[1][ni] = __builtin_amdgcn_mfma_f32_16x16x32_bf16(a1, bb, acc[1][ni], 0, 0, 0);
        }
    }

#pragma unroll
    for (int mi = 0; mi < 2; ++mi)
#pragma unroll
        for (int ni = 0; ni < 4; ++ni) {
            int cc = w * 64 + ni * 16 + lm;
#pragma unroll
            for (int r = 0; r < 4; ++r) {
                int m = mi * 16 + lq * 4 + r;
                Df[m * 260 + cc] = acc[mi][ni][r];
            }
        }
    __syncthreads();

    // epilogue: one thread per output channel
    const int cc = tid;
    const float inv  = bn_g[cc] * rsqrtf(bn_v[cc] + BN_EPS);
    const float bias = (wz_b[cc] - bn_m[cc]) * inv + bn_b[cc];

    const float4* xp = (const float4*)(x   + ((size_t)b * CH + cc) * NPIX + n0);
    float4*       op = (float4*)      (out + ((size_t)b * CH + cc) * NPIX + n0);
#pragma unroll
    for (int n4 = 0; n4 < 8; ++n4) {
        float4 xv = xp[n4];
        float4 ov;
        ov.x = Df[(n4 * 4 + 0) * 260 + cc] * inv + bias + xv.x;
        ov.y = Df[(n4 * 4 + 1) * 260 + cc] * inv + bias + xv.y;
        ov.z = Df[(n4 * 4 + 2) * 260 + cc] * inv + bias + xv.z;
        ov.w = Df[(n4 * 4 + 3) * 260 + cc] * inv + bias + xv.w;
        op[n4] = ov;
    }
}

// ---------------------------------------------------------------------------
extern "C" void kernel_launch(void* const* d_in, const int* in_sizes, int n_in,
                              void* d_out, int out_size, void* d_ws, size_t ws_size,
                              hipStream_t stream)
{
    const float* x       = (const float*)d_in[0];
    const float* g_w     = (const float*)d_in[1];
    const float* g_b     = (const float*)d_in[2];
    const float* theta_w = (const float*)d_in[3];
    const float* theta_b = (const float*)d_in[4];
    const float* phi_w   = (const float*)d_in[5];
    const float* phi_b   = (const float*)d_in[6];
    const float* wf_w    = (const float*)d_in[7];
    const float* wf_b    = (const float*)d_in[8];
    const float* wz_w    = (const float*)d_in[9];
    const float* wz_b    = (const float*)d_in[10];
    const float* bn_g    = (const float*)d_in[11];
    const float* bn_b    = (const float*)d_in[12];
    const float* bn_m    = (const float*)d_in[13];
    const float* bn_v    = (const float*)d_in[14];

    float* ws = (float*)d_ws;
    float* ta_w   = ws;                                    // 256
    float* pb_w   = ws + 256;                              // 256
    float* biases = ws + 512;                              // 4
    unsigned* mmx = (unsigned*)(ws + 516);                 // 16
    float* a_arr  = ws + 532;                              // 8*3136
    float* bsc    = a_arr + BATCH * NPIX;                  // 8*3136
    float* CSP    = bsc + BATCH * NPIX;                    // 8*130*128*2 floats
    unsigned short* Bfrag_g = (unsigned short*)(CSP + BATCH * CSROWS * CI * 2); // 32768
    unsigned short* Bfrag_w = Bfrag_g + 32768;             // 32768
    unsigned short* gxg = Bfrag_w + 32768;                 // 8*3136*128 bf16

    k_fold<<<33, 256, 0, stream>>>(wf_w, theta_w, theta_b, phi_w, phi_b,
                                   g_w, wz_w, ta_w, pb_w, biases,
                                   mmx, CSP, Bfrag_g, Bfrag_w);

    k_gemm<<<dim3(NCHUNK, BATCH), 256, 0, stream>>>(
        x, Bfrag_g, g_b, ta_w, pb_w, biases, gxg, a_arr, bsc, mmx);

    k_binsum<<<dim3(NCHUNK, BATCH), 256, 0, stream>>>(
        gxg, bsc, mmx, CSP);

    k_suffix<<<BATCH, 256, 0, stream>>>(CSP);

    k_final<<<dim3(NCHUNK, BATCH), 256, 0, stream>>>(
        x, a_arr, wf_b, CSP, mmx, Bfrag_w,
        wz_b, bn_g, bn_b, bn_m, bn_v, (float*)d_out);
}